// Round 8
// baseline (2290.482 us; speedup 1.0000x reference)
//
#include <hip/hip_runtime.h>
#include <hip/hip_bf16.h>
#include <hip/hip_cooperative_groups.h>

namespace cg = cooperative_groups;

constexpr int B = 512;
constexpr int I = 512;
constexpr int H = 1024;
constexpr int O = 512;

using short8 = __attribute__((ext_vector_type(8))) short;
using f32x4  = __attribute__((ext_vector_type(4))) float;
using bf16_t = __hip_bfloat16;

__device__ __forceinline__ short8 ldfrag(const bf16_t* p) {
    return *reinterpret_cast<const short8*>(p);
}
__device__ __forceinline__ float sigmoid_f(float z) {
    return 1.0f / (1.0f + __expf(-z));
}

// Per-iblk group barrier. Group = 64 WGs with the same (blockIdx % 8) -> one
// XCD under round-robin dispatch; its L2 is the coherence point for h.
// Only per-CU L1 needs invalidation (stale h-buffer lines).
__device__ __forceinline__ void group_wait(int* c, int target) {
    if (threadIdx.x == 0) {
        while (__hip_atomic_load(c, __ATOMIC_RELAXED, __HIP_MEMORY_SCOPE_AGENT) < target)
            __builtin_amdgcn_s_sleep(2);
    }
    __syncthreads();
    asm volatile("buffer_inv sc0" ::: "memory");   // L1-only invalidate
}
__device__ __forceinline__ void group_post(int* c) {
    __syncthreads();  // drains this WG's h stores to local L2 (vmcnt 0)
    if (threadIdx.x == 0)
        __hip_atomic_fetch_add(c, 1, __ATOMIC_RELAXED, __HIP_MEMORY_SCOPE_AGENT);
}

// 512 WGs x 256 thr, 64KB LDS (Wjh+Wkh slices), 2 WGs/CU.
// WG(g): iblk = g&7 (64 batch rows, XCD-local group), lblk = g>>3 (16 gate cols).
// lblk<32 WGs additionally compute 16 out cols (deferred past the barrier post).
// h is triple-buffered so the deferred out-GEMM read of h_t can never be
// overwritten (buffer t%3 rewritten only at step t+2, gated on our own post).
// LDS B-stride per MFMA k-step = 512 shorts (4 kb-chunks of [col][8]);
// R5/R7 used 128 (one chunk) -> wrong weights -> deterministic absmax 0.52.
__global__ __launch_bounds__(256, 2)
void flipflop_rnn_kernel(const float* __restrict__ x,  const float* __restrict__ h0,
                         const float* __restrict__ Wjx, const float* __restrict__ bjx,
                         const float* __restrict__ Wjh, const float* __restrict__ bjh,
                         const float* __restrict__ Wkx, const float* __restrict__ bkx,
                         const float* __restrict__ Wkh, const float* __restrict__ bkh,
                         const float* __restrict__ Wo,  const float* __restrict__ bo,
                         const int* __restrict__ seqlen,
                         float* __restrict__ out,
                         bf16_t* __restrict__ wjh_bf, bf16_t* __restrict__ wkh_bf,
                         bf16_t* __restrict__ wo_bf,  bf16_t* __restrict__ wjx_bf,
                         bf16_t* __restrict__ wkx_bf, bf16_t* __restrict__ x_bf,
                         bf16_t* __restrict__ hbf0,   bf16_t* __restrict__ hbf1,
                         bf16_t* __restrict__ hbf2,   int* __restrict__ cnt)
{
    // [gate][kb 0..127][col 0..15][8 shorts] = 65536 B
    __shared__ short lds_w[32768];

    const int T    = seqlen[0];
    const int tid  = threadIdx.x;
    const int g    = blockIdx.x;
    const int nthr = gridDim.x * blockDim.x;
    const int gtid = g * blockDim.x + tid;

    // ---- cast weights & x to bf16; zero barrier counters ----
    for (int idx = gtid; idx < H * H; idx += nthr) wjh_bf[idx] = __float2bfloat16(Wjh[idx]);
    for (int idx = gtid; idx < H * H; idx += nthr) wkh_bf[idx] = __float2bfloat16(Wkh[idx]);
    for (int idx = gtid; idx < O * H; idx += nthr) wo_bf[idx]  = __float2bfloat16(Wo[idx]);
    for (int idx = gtid; idx < H * I; idx += nthr) wjx_bf[idx] = __float2bfloat16(Wjx[idx]);
    for (int idx = gtid; idx < H * I; idx += nthr) wkx_bf[idx] = __float2bfloat16(Wkx[idx]);
    for (int idx = gtid; idx < B * I; idx += nthr) x_bf[idx]   = __float2bfloat16(x[idx]);
    if (gtid < 8 * 256) cnt[gtid] = 0;

    // ---- geometry ----
    const int w     = tid >> 6;
    const int lane  = tid & 63;
    const int quad  = lane >> 4;
    const int lm    = lane & 15;
    const int iblk  = g & 7;            // XCD-local group id
    const int lblk  = g >> 3;           // 0..63
    const int rbase = iblk * 64 + w * 16;
    const int n0    = lblk * 16;        // gate cols
    const bool has_out = (lblk < 32);
    const int no0   = lblk * 16;        // out cols (valid when has_out)
    int* grp_cnt = cnt + iblk * 256;

    // ---- h0 init: each thread owns 4 (row,col) elements ----
    float hreg[4];
    #pragma unroll
    for (int r = 0; r < 4; ++r) {
        const int row = rbase + quad * 4 + r;
        const int col = n0 + lm;
        const float hv = h0[row * H + col];
        hreg[r] = hv;
        hbf0[row * H + col] = __float2bfloat16(hv);
    }

    cg::this_grid().sync();   // casts + h0 + cnt zero visible device-wide

    // ---- load this WG's Wjh/Wkh rows into LDS (one time) ----
    for (int c = tid; c < 4096; c += 256) {
        const int gate = c >> 11;
        const int cc   = c & 2047;
        const int kb   = cc >> 4;
        const int col  = cc & 15;
        const bf16_t* src = (gate ? wkh_bf : wjh_bf) + (n0 + col) * H + kb * 8;
        *reinterpret_cast<short8*>(&lds_w[c * 8]) = *reinterpret_cast<const short8*>(src);
    }
    __syncthreads();

    // ---- jx/kx (+ all biases) in registers ----
    float jxr[4], kxr[4];
    {
        f32x4 aJ = {0.f, 0.f, 0.f, 0.f};
        f32x4 aK = {0.f, 0.f, 0.f, 0.f};
        const bf16_t* aP = x_bf   + (rbase + lm) * I + quad * 8;
        const bf16_t* jP = wjx_bf + (n0 + lm) * I + quad * 8;
        const bf16_t* kP = wkx_bf + (n0 + lm) * I + quad * 8;
        #pragma unroll 4
        for (int k0 = 0; k0 < I; k0 += 32) {
            short8 a = ldfrag(aP + k0);
            aJ = __builtin_amdgcn_mfma_f32_16x16x32_bf16(a, ldfrag(jP + k0), aJ, 0, 0, 0);
            aK = __builtin_amdgcn_mfma_f32_16x16x32_bf16(a, ldfrag(kP + k0), aK, 0, 0, 0);
        }
        const int col = n0 + lm;
        #pragma unroll
        for (int r = 0; r < 4; ++r) {
            jxr[r] = aJ[r] + bjx[col] + bjh[col];
            kxr[r] = aK[r] + bkx[col] + bkh[col];
        }
    }
    const float bo_v = has_out ? bo[no0 + lm] : 0.0f;

    constexpr int PF = 8;   // A-fragment prefetch depth (~400+ cyc L2 cover)
    bf16_t* hbufs[3] = {hbf0, hbf1, hbf2};

    // ---- recurrence: step t reads h_t -> h_{t+1}; out_{t-1} deferred ----
    for (int t = 0; t < T; ++t) {
        if (t > 0) group_wait(grp_cnt + t, 64);   // h_t published by all 64 group WGs
        const bf16_t* hb  = hbufs[t % 3];
        bf16_t*       hbn = hbufs[(t + 1) % 3];

        const bf16_t* aP = hb + (rbase + lm) * H + quad * 8;
        const short*  jL = lds_w + quad * 128 + lm * 8;          // [kb][col][8]
        const short*  kL = jL + 16384;

        // --- gate GEMM with depth-PF software pipeline (critical path) ---
        f32x4 accJ = {0.f, 0.f, 0.f, 0.f};
        f32x4 accK = {0.f, 0.f, 0.f, 0.f};
        short8 af[PF];
        #pragma unroll
        for (int i = 0; i < PF; ++i) af[i] = ldfrag(aP + i * 32);
        #pragma unroll
        for (int k = 0; k < 32; ++k) {
            short8 a = af[k & (PF - 1)];
            if (k + PF < 32) af[k & (PF - 1)] = ldfrag(aP + (k + PF) * 32);
            short8 bj = *reinterpret_cast<const short8*>(jL + k * 512);  // 4 kb-chunks / MFMA
            short8 bk = *reinterpret_cast<const short8*>(kL + k * 512);
            accJ = __builtin_amdgcn_mfma_f32_16x16x32_bf16(a, bj, accJ, 0, 0, 0);
            accK = __builtin_amdgcn_mfma_f32_16x16x32_bf16(a, bk, accK, 0, 0, 0);
        }

        // --- h update + publish h_{t+1} ---
        #pragma unroll
        for (int r = 0; r < 4; ++r) {
            const int row = rbase + quad * 4 + r;
            const int col = n0 + lm;
            const float jv = sigmoid_f(accJ[r] + jxr[r]);
            const float kv = sigmoid_f(accK[r] + kxr[r]);
            const float hv = hreg[r];
            const float hn = jv * (1.0f - hv) + (1.0f - kv) * hv;
            hreg[r] = hn;
            hbn[row * H + col] = __float2bfloat16(hn);
        }
        group_post(grp_cnt + t + 1);   // publish h_{t+1}

        // --- deferred out_{t-1} = h_t @ Wo^T (off critical path; safe under
        //     triple buffering: buffer t%3 rewritten only after all post t+2) ---
        if (has_out && t > 0) {
            f32x4 accO = {0.f, 0.f, 0.f, 0.f};
            const bf16_t* oP = wo_bf + (no0 + lm) * H + quad * 8;
            short8 aof[PF], wof[PF];
            #pragma unroll
            for (int i = 0; i < PF; ++i) { aof[i] = ldfrag(aP + i * 32); wof[i] = ldfrag(oP + i * 32); }
            #pragma unroll
            for (int k = 0; k < 32; ++k) {
                short8 a  = aof[k & (PF - 1)];
                short8 wo = wof[k & (PF - 1)];
                if (k + PF < 32) {
                    aof[k & (PF - 1)] = ldfrag(aP + (k + PF) * 32);
                    wof[k & (PF - 1)] = ldfrag(oP + (k + PF) * 32);
                }
                accO = __builtin_amdgcn_mfma_f32_16x16x32_bf16(a, wo, accO, 0, 0, 0);
            }
            #pragma unroll
            for (int r = 0; r < 4; ++r) {
                const int row = rbase + quad * 4 + r;
                out[(row * T + (t - 1)) * O + no0 + lm] = accO[r] + bo_v;
            }
        }
    }

    group_wait(grp_cnt + T, 64);       // h_T published

    // ---- epilogue: out_{T-1} and h_final ----
    {
        const bf16_t* hb = hbufs[T % 3];
        if (has_out) {
            f32x4 accO = {0.f, 0.f, 0.f, 0.f};
            const bf16_t* aP = hb    + (rbase + lm) * H + quad * 8;
            const bf16_t* oP = wo_bf + (no0 + lm) * H + quad * 8;
            #pragma unroll 4
            for (int k0 = 0; k0 < H; k0 += 32) {
                accO = __builtin_amdgcn_mfma_f32_16x16x32_bf16(ldfrag(aP + k0), ldfrag(oP + k0), accO, 0, 0, 0);
            }
            #pragma unroll
            for (int r = 0; r < 4; ++r) {
                const int row = rbase + quad * 4 + r;
                out[(row * T + (T - 1)) * O + no0 + lm] = accO[r] + bo_v;
            }
        }
        const int hfin = B * T * O;
        #pragma unroll
        for (int r = 0; r < 4; ++r) {
            const int row = rbase + quad * 4 + r;
            const int col = n0 + lm;
            out[hfin + row * H + col] = hreg[r];
        }
    }
}

extern "C" void kernel_launch(void* const* d_in, const int* in_sizes, int n_in,
                              void* d_out, int out_size, void* d_ws, size_t ws_size,
                              hipStream_t stream) {
    const float* x   = (const float*)d_in[0];
    const float* h0  = (const float*)d_in[1];
    const float* Wjx = (const float*)d_in[2];
    const float* bjx = (const float*)d_in[3];
    const float* Wjh = (const float*)d_in[4];
    const float* bjh = (const float*)d_in[5];
    const float* Wkx = (const float*)d_in[6];
    const float* bkx = (const float*)d_in[7];
    const float* Wkh = (const float*)d_in[8];
    const float* bkh = (const float*)d_in[9];
    const float* Wo  = (const float*)d_in[10];
    const float* bo  = (const float*)d_in[11];
    const int* seqlen = (const int*)d_in[12];
    float* out = (float*)d_out;

    // workspace layout (bytes)
    char* ws = (char*)d_ws;
    bf16_t* wjh_bf = (bf16_t*)(ws + 0);                 // 2 MB
    bf16_t* wkh_bf = (bf16_t*)(ws + 2097152);           // 2 MB
    bf16_t* wo_bf  = (bf16_t*)(ws + 4194304);           // 1 MB
    bf16_t* wjx_bf = (bf16_t*)(ws + 5242880);           // 1 MB
    bf16_t* wkx_bf = (bf16_t*)(ws + 6291456);           // 1 MB
    bf16_t* x_bf   = (bf16_t*)(ws + 7340032);           // 0.5 MB
    bf16_t* hbf0   = (bf16_t*)(ws + 7864320);           // 1 MB
    bf16_t* hbf1   = (bf16_t*)(ws + 8912896);           // 1 MB
    bf16_t* hbf2   = (bf16_t*)(ws + 9961472);           // 1 MB
    int*    cnt    = (int*)   (ws + 11010048);          // 8 KB barrier counters

    void* args[] = {
        &x, &h0, &Wjx, &bjx, &Wjh, &bjh, &Wkx, &bkx, &Wkh, &bkh, &Wo, &bo,
        &seqlen, &out,
        &wjh_bf, &wkh_bf, &wo_bf, &wjx_bf, &wkx_bf, &x_bf, &hbf0, &hbf1, &hbf2, &cnt
    };
    hipLaunchCooperativeKernel((const void*)flipflop_rnn_kernel,
                               dim3(512), dim3(256), args, 0, stream);
}